// Round 2
// baseline (4206.830 us; speedup 1.0000x reference)
//
#include <hip/hip_runtime.h>
#include <hip/hip_bf16.h>
#include <math.h>

// Problem constants
#define BB 2
#define TT 4096
#define DM 1024
#define DSTATE 128
#define DCONV 4
#define DI 2048
#define HD 64
#define NH 32
#define DIP 4384   // 2*DI + 2*DSTATE + NH
#define CD 2304    // DI + 2*DSTATE

// ---------------- Kernel 1: LayerNorm statistics (mu, rsqrt(var+eps)) ----------------
__global__ __launch_bounds__(64) void ln_stats_kernel(const float* __restrict__ x,
                                                      float* __restrict__ mu,
                                                      float* __restrict__ rs) {
    int t = blockIdx.x * 64 + threadIdx.x;
    int b = blockIdx.y;
    const float* xb = x + (size_t)b * DM * TT + t;
    float s = 0.f, ss = 0.f;
#pragma unroll 8
    for (int d = 0; d < DM; d++) {
        float v = xb[(size_t)d * TT];
        s += v;
        ss += v * v;
    }
    float m = s * (1.f / DM);
    float var = ss * (1.f / DM) - m * m;
    int idx = b * TT + t;
    mu[idx] = m;
    rs[idx] = rsqrtf(var + 1e-5f);
}

// ---------------- Kernel 2: GEMM1 with fused LayerNorm affine ----------------
// zx[m, j] = sum_k ((x[b,k,t]-mu[m])*rs[m]*ln_w[k]+ln_b[k]) * W_in[j,k]
__global__ __launch_bounds__(256) void gemm1_kernel(const float* __restrict__ x,
                                                    const float* __restrict__ mu,
                                                    const float* __restrict__ rs,
                                                    const float* __restrict__ ln_w,
                                                    const float* __restrict__ ln_b,
                                                    const float* __restrict__ Win,
                                                    float* __restrict__ zx) {
    __shared__ float As[16][64];      // [k][m] tile
    __shared__ float Ws[64][17];      // [j][k] tile (padded)
    int tid = threadIdx.x;
    int tx = tid & 15;    // n(j)-dim
    int ty = tid >> 4;    // m-dim
    int j0 = blockIdx.x * 64;
    int m0 = blockIdx.y * 64;
    int b = m0 >> 12;
    int t0 = m0 & 4095;
    const float* Xb = x + (size_t)b * DM * TT + t0;

    int lr = tid >> 4;          // As row (k)
    int lc = (tid & 15) * 4;    // As col (m)
    int wr = tid >> 2;          // Ws row (j)
    int wc = (tid & 3) * 4;     // Ws col (k)

    float acc[4][4] = {};
    for (int k0 = 0; k0 < DM; k0 += 16) {
        float4 xv = *(const float4*)(Xb + (size_t)(k0 + lr) * TT + lc);
        float4 muv = *(const float4*)(&mu[m0 + lc]);
        float4 rsv = *(const float4*)(&rs[m0 + lc]);
        float lw = ln_w[k0 + lr], lb = ln_b[k0 + lr];
        As[lr][lc]     = (xv.x - muv.x) * rsv.x * lw + lb;
        As[lr][lc + 1] = (xv.y - muv.y) * rsv.y * lw + lb;
        As[lr][lc + 2] = (xv.z - muv.z) * rsv.z * lw + lb;
        As[lr][lc + 3] = (xv.w - muv.w) * rsv.w * lw + lb;

        int j = j0 + wr;
        float4 wv = make_float4(0.f, 0.f, 0.f, 0.f);
        if (j < DIP) wv = *(const float4*)(Win + (size_t)j * DM + k0 + wc);
        Ws[wr][wc] = wv.x; Ws[wr][wc + 1] = wv.y; Ws[wr][wc + 2] = wv.z; Ws[wr][wc + 3] = wv.w;
        __syncthreads();
#pragma unroll
        for (int kk = 0; kk < 16; kk++) {
            float4 a4 = *(const float4*)&As[kk][ty * 4];
            float a[4] = {a4.x, a4.y, a4.z, a4.w};
            float bv[4];
#pragma unroll
            for (int n = 0; n < 4; n++) bv[n] = Ws[tx * 4 + n][kk];
#pragma unroll
            for (int i = 0; i < 4; i++)
#pragma unroll
                for (int n = 0; n < 4; n++)
                    acc[i][n] = fmaf(a[i], bv[n], acc[i][n]);
        }
        __syncthreads();
    }
#pragma unroll
    for (int i = 0; i < 4; i++) {
        int m = m0 + ty * 4 + i;
        int j = j0 + tx * 4;
        if (j < DIP) {
            float4 v = make_float4(acc[i][0], acc[i][1], acc[i][2], acc[i][3]);
            *(float4*)(zx + (size_t)m * DIP + j) = v;
        }
    }
}

// ---------------- Kernel 3: causal depthwise conv(4) + SiLU ----------------
__global__ __launch_bounds__(256) void conv_kernel(const float* __restrict__ zx,
                                                   const float* __restrict__ cw,
                                                   const float* __restrict__ cb,
                                                   float* __restrict__ xBC) {
    int i = blockIdx.x * 256 + threadIdx.x;      // over B*T*CD
    int c = i % CD;
    int t = (i / CD) & (TT - 1);
    int b = i / (CD * TT);
    const float* src = zx + (size_t)b * TT * DIP + DI + c;
    float acc = cb[c];
#pragma unroll
    for (int k = 0; k < 4; k++) {
        int ts = t - 3 + k;
        if (ts >= 0) acc = fmaf(cw[c * 4 + k], src[(size_t)ts * DIP], acc);
    }
    float sg = 1.f / (1.f + expf(-acc));
    xBC[(size_t)i] = acc * sg;
}

// ---------------- Kernel 4: dt softplus + dA ----------------
__global__ __launch_bounds__(256) void dt_kernel(const float* __restrict__ zx,
                                                 const float* __restrict__ dt_bias,
                                                 const float* __restrict__ A_log,
                                                 float* __restrict__ dtv,
                                                 float* __restrict__ dAb) {
    int i = blockIdx.x * 256 + threadIdx.x;     // over B*T*NH
    int hh = i & (NH - 1);
    int m = i >> 5;
    float raw = zx[(size_t)m * DIP + (DI + CD) + hh] + dt_bias[hh];
    float dt = (raw > 20.f) ? raw : log1pf(expf(raw));
    float dA = expf(-expf(A_log[hh]) * dt);
    dtv[i] = dt;
    dAb[i] = dA;
}

// ---------------- Kernel 5: selective scan ----------------
// ys is written into zx columns [2048,4096) (stride DIP) — those cols are dead
// after conv+dt have consumed them (stream order guarantees this).
__global__ __launch_bounds__(64) void scan_kernel(const float* __restrict__ xBC,
                                                  const float* __restrict__ dAb,
                                                  const float* __restrict__ dtv,
                                                  const float* __restrict__ h0,
                                                  const float* __restrict__ Dp,
                                                  float* __restrict__ zx,
                                                  float* __restrict__ hT) {
    int lane = threadIdx.x;
    int pl = lane >> 4;
    int jg = lane & 15;
    int pc = blockIdx.x, hh = blockIdx.y, b = blockIdx.z;
    int p = pc * 4 + pl;
    int n0 = jg * 8;

    float h[8];
    const float* h0p = h0 + ((size_t)((b * NH + hh) * HD + p)) * DSTATE + n0;
    float4 ha = *(const float4*)h0p;
    float4 hb2 = *(const float4*)(h0p + 4);
    h[0] = ha.x; h[1] = ha.y; h[2] = ha.z; h[3] = ha.w;
    h[4] = hb2.x; h[5] = hb2.y; h[6] = hb2.z; h[7] = hb2.w;

    float Dh = Dp[hh];
    const float* base = xBC + (size_t)b * TT * CD;
    const float* dab = dAb + (size_t)b * TT * NH + hh;
    const float* dtb = dtv + (size_t)b * TT * NH + hh;
    float* yb = zx + (size_t)b * TT * DIP + DI + hh * HD + p;

    float4 B0 = *(const float4*)(base + DI + n0);
    float4 B1 = *(const float4*)(base + DI + n0 + 4);
    float4 C0 = *(const float4*)(base + DI + DSTATE + n0);
    float4 C1 = *(const float4*)(base + DI + DSTATE + n0 + 4);
    float xin = base[hh * HD + p];
    float da = dab[0], dt = dtb[0];

    for (int t = 0; t < TT; t++) {
        int tn = (t + 1 < TT) ? (t + 1) : t;
        const float* rn = base + (size_t)tn * CD;
        float4 nB0 = *(const float4*)(rn + DI + n0);
        float4 nB1 = *(const float4*)(rn + DI + n0 + 4);
        float4 nC0 = *(const float4*)(rn + DI + DSTATE + n0);
        float4 nC1 = *(const float4*)(rn + DI + DSTATE + n0 + 4);
        float nx = rn[hh * HD + p];
        float nda = dab[(size_t)tn * NH];
        float ndt = dtb[(size_t)tn * NH];

        float xdt = xin * dt;
        float ps;
        h[0] = fmaf(h[0], da, xdt * B0.x); ps = h[0] * C0.x;
        h[1] = fmaf(h[1], da, xdt * B0.y); ps = fmaf(h[1], C0.y, ps);
        h[2] = fmaf(h[2], da, xdt * B0.z); ps = fmaf(h[2], C0.z, ps);
        h[3] = fmaf(h[3], da, xdt * B0.w); ps = fmaf(h[3], C0.w, ps);
        h[4] = fmaf(h[4], da, xdt * B1.x); ps = fmaf(h[4], C1.x, ps);
        h[5] = fmaf(h[5], da, xdt * B1.y); ps = fmaf(h[5], C1.y, ps);
        h[6] = fmaf(h[6], da, xdt * B1.z); ps = fmaf(h[6], C1.z, ps);
        h[7] = fmaf(h[7], da, xdt * B1.w); ps = fmaf(h[7], C1.w, ps);

        ps += __shfl_xor(ps, 1);
        ps += __shfl_xor(ps, 2);
        ps += __shfl_xor(ps, 4);
        ps += __shfl_xor(ps, 8);
        if (jg == 0) yb[(size_t)t * DIP] = ps + Dh * xin;

        B0 = nB0; B1 = nB1; C0 = nC0; C1 = nC1;
        xin = nx; da = nda; dt = ndt;
    }
    float* hp = hT + ((size_t)((b * NH + hh) * HD + p)) * DSTATE + n0;
    *(float4*)hp = make_float4(h[0], h[1], h[2], h[3]);
    *(float4*)(hp + 4) = make_float4(h[4], h[5], h[6], h[7]);
}

// ---------------- Kernel 6: gating + RMSNorm (in-place over z cols of zx) ----------------
__global__ __launch_bounds__(256) void gate_rms_kernel(float* __restrict__ zx,
                                                       const float* __restrict__ rw) {
    int m = blockIdx.x;
    int tid = threadIdx.x;
    const float* yr = zx + (size_t)m * DIP + DI;
    float* zr = zx + (size_t)m * DIP;
    float gv[8];
    float ss = 0.f;
#pragma unroll
    for (int i = 0; i < 8; i++) {
        int idx = tid + i * 256;
        float y = yr[idx];
        float z = zr[idx];
        float sg = 1.f / (1.f + expf(-z));
        float gg = y * z * sg;
        gv[i] = gg;
        ss += gg * gg;
    }
#pragma unroll
    for (int off = 1; off < 64; off <<= 1) ss += __shfl_xor(ss, off);
    __shared__ float red[4];
    int w = tid >> 6;
    if ((tid & 63) == 0) red[w] = ss;
    __syncthreads();
    float tot = red[0] + red[1] + red[2] + red[3];
    float r = rsqrtf(tot * (1.f / DI) + 1e-5f);
#pragma unroll
    for (int i = 0; i < 8; i++) {
        int idx = tid + i * 256;
        zr[idx] = gv[i] * r * rw[idx];
    }
}

// ---------------- Kernel 7: GEMM2 (out-proj, transposed store) ----------------
// g lives in zx cols [0,2048) with row stride DIP.
__global__ __launch_bounds__(256) void gemm2_kernel(const float* __restrict__ g,
                                                    const float* __restrict__ Wout,
                                                    float* __restrict__ out) {
    __shared__ float Gs[64][17];
    __shared__ float Ws[64][17];
    int tid = threadIdx.x;
    int tx = tid & 15;    // m-dim
    int ty = tid >> 4;    // n(j)-dim
    int j0 = blockIdx.x * 64;
    int m0 = blockIdx.y * 64;
    int b = m0 >> 12;
    int t0 = m0 & 4095;
    int r = tid >> 2;
    int c = (tid & 3) * 4;
    float acc[4][4] = {};
    for (int k0 = 0; k0 < DI; k0 += 16) {
        float4 gv = *(const float4*)(g + (size_t)(m0 + r) * DIP + k0 + c);
        Gs[r][c] = gv.x; Gs[r][c + 1] = gv.y; Gs[r][c + 2] = gv.z; Gs[r][c + 3] = gv.w;
        float4 wv = *(const float4*)(Wout + (size_t)(j0 + r) * DI + k0 + c);
        Ws[r][c] = wv.x; Ws[r][c + 1] = wv.y; Ws[r][c + 2] = wv.z; Ws[r][c + 3] = wv.w;
        __syncthreads();
#pragma unroll
        for (int kk = 0; kk < 16; kk++) {
            float a[4], bv[4];
#pragma unroll
            for (int i = 0; i < 4; i++) a[i] = Gs[tx * 4 + i][kk];
#pragma unroll
            for (int n = 0; n < 4; n++) bv[n] = Ws[ty * 4 + n][kk];
#pragma unroll
            for (int i = 0; i < 4; i++)
#pragma unroll
                for (int n = 0; n < 4; n++)
                    acc[i][n] = fmaf(a[i], bv[n], acc[i][n]);
        }
        __syncthreads();
    }
#pragma unroll
    for (int n = 0; n < 4; n++) {
        int j = j0 + ty * 4 + n;
        float4 v = make_float4(acc[0][n], acc[1][n], acc[2][n], acc[3][n]);
        *(float4*)(out + (size_t)b * DM * TT + (size_t)j * TT + t0 + tx * 4) = v;
    }
}

extern "C" void kernel_launch(void* const* d_in, const int* in_sizes, int n_in,
                              void* d_out, int out_size, void* d_ws, size_t ws_size,
                              hipStream_t stream) {
    const float* x       = (const float*)d_in[0];
    const float* ln_w    = (const float*)d_in[1];
    const float* ln_b    = (const float*)d_in[2];
    const float* W_in    = (const float*)d_in[3];
    const float* conv_w  = (const float*)d_in[4];
    const float* conv_b  = (const float*)d_in[5];
    const float* dt_bias = (const float*)d_in[6];
    const float* A_log   = (const float*)d_in[7];
    const float* Dp      = (const float*)d_in[8];
    const float* rms_w   = (const float*)d_in[9];
    const float* W_out   = (const float*)d_in[10];
    const float* h0      = (const float*)d_in[11];

    float* out = (float*)d_out;
    float* hT = out + (size_t)BB * DM * TT;   // 8,388,608 floats in, then 524,288 for hT

    char* ws = (char*)d_ws;
    // workspace layout (bytes) — total 221,315,072 (~211 MiB):
    float* mu  = (float*)(ws + 0);            //      32,768
    float* rs  = (float*)(ws + 32768);        //      32,768
    float* zx  = (float*)(ws + 65536);        // 143,654,912  (B,T,4384)
    float* xBC = (float*)(ws + 143720448);    //  75,497,472  (B,T,2304)
    float* dAb = (float*)(ws + 219217920);    //   1,048,576  (B,T,32)
    float* dtv = (float*)(ws + 220266496);    //   1,048,576  (B,T,32)

    ln_stats_kernel<<<dim3(TT / 64, BB), 64, 0, stream>>>(x, mu, rs);
    gemm1_kernel<<<dim3((DIP + 63) / 64, (BB * TT) / 64), 256, 0, stream>>>(
        x, mu, rs, ln_w, ln_b, W_in, zx);
    conv_kernel<<<(BB * TT * CD) / 256, 256, 0, stream>>>(zx, conv_w, conv_b, xBC);
    dt_kernel<<<(BB * TT * NH) / 256, 256, 0, stream>>>(zx, dt_bias, A_log, dtv, dAb);
    scan_kernel<<<dim3(16, NH, BB), 64, 0, stream>>>(xBC, dAb, dtv, h0, Dp, zx, hT);
    gate_rms_kernel<<<BB * TT, 256, 0, stream>>>(zx, rms_w);
    gemm2_kernel<<<dim3(DM / 64, (BB * TT) / 64), 256, 0, stream>>>(zx, W_out, out);
}

// Round 3
// 4043.909 us; speedup vs baseline: 1.0403x; 1.0403x over previous
//
#include <hip/hip_runtime.h>
#include <hip/hip_bf16.h>
#include <math.h>

// Problem constants
#define BB 2
#define TT 4096
#define DM 1024
#define DSTATE 128
#define DCONV 4
#define DI 2048
#define HD 64
#define NH 32
#define DIP 4384   // 2*DI + 2*DSTATE + NH
#define CD 2304    // DI + 2*DSTATE

// ---------------- Kernel 1: LayerNorm statistics (mu, rsqrt(var+eps)) ----------------
__global__ __launch_bounds__(64) void ln_stats_kernel(const float* __restrict__ x,
                                                      float* __restrict__ mu,
                                                      float* __restrict__ rs) {
    int t = blockIdx.x * 64 + threadIdx.x;
    int b = blockIdx.y;
    const float* xb = x + (size_t)b * DM * TT + t;
    float s = 0.f, ss = 0.f;
#pragma unroll 8
    for (int d = 0; d < DM; d++) {
        float v = xb[(size_t)d * TT];
        s += v;
        ss += v * v;
    }
    float m = s * (1.f / DM);
    float var = ss * (1.f / DM) - m * m;
    int idx = b * TT + t;
    mu[idx] = m;
    rs[idx] = rsqrtf(var + 1e-5f);
}

// ---------------- Kernel 2: GEMM1 with fused LayerNorm affine ----------------
// zx[m, j] = sum_k ((x[b,k,t]-mu[m])*rs[m]*ln_w[k]+ln_b[k]) * W_in[j,k]
__global__ __launch_bounds__(256) void gemm1_kernel(const float* __restrict__ x,
                                                    const float* __restrict__ mu,
                                                    const float* __restrict__ rs,
                                                    const float* __restrict__ ln_w,
                                                    const float* __restrict__ ln_b,
                                                    const float* __restrict__ Win,
                                                    float* __restrict__ zx) {
    __shared__ float As[16][64];      // [k][m] tile
    __shared__ float Ws[64][17];      // [j][k] tile (padded)
    int tid = threadIdx.x;
    int tx = tid & 15;    // n(j)-dim
    int ty = tid >> 4;    // m-dim
    int j0 = blockIdx.x * 64;
    int m0 = blockIdx.y * 64;
    int b = m0 >> 12;
    int t0 = m0 & 4095;
    const float* Xb = x + (size_t)b * DM * TT + t0;

    int lr = tid >> 4;          // As row (k)
    int lc = (tid & 15) * 4;    // As col (m)
    int wr = tid >> 2;          // Ws row (j)
    int wc = (tid & 3) * 4;     // Ws col (k)

    float acc[4][4] = {};
    for (int k0 = 0; k0 < DM; k0 += 16) {
        float4 xv = *(const float4*)(Xb + (size_t)(k0 + lr) * TT + lc);
        float4 muv = *(const float4*)(&mu[m0 + lc]);
        float4 rsv = *(const float4*)(&rs[m0 + lc]);
        float lw = ln_w[k0 + lr], lb = ln_b[k0 + lr];
        As[lr][lc]     = (xv.x - muv.x) * rsv.x * lw + lb;
        As[lr][lc + 1] = (xv.y - muv.y) * rsv.y * lw + lb;
        As[lr][lc + 2] = (xv.z - muv.z) * rsv.z * lw + lb;
        As[lr][lc + 3] = (xv.w - muv.w) * rsv.w * lw + lb;

        int j = j0 + wr;
        float4 wv = make_float4(0.f, 0.f, 0.f, 0.f);
        if (j < DIP) wv = *(const float4*)(Win + (size_t)j * DM + k0 + wc);
        Ws[wr][wc] = wv.x; Ws[wr][wc + 1] = wv.y; Ws[wr][wc + 2] = wv.z; Ws[wr][wc + 3] = wv.w;
        __syncthreads();
#pragma unroll
        for (int kk = 0; kk < 16; kk++) {
            float4 a4 = *(const float4*)&As[kk][ty * 4];
            float a[4] = {a4.x, a4.y, a4.z, a4.w};
            float bv[4];
#pragma unroll
            for (int n = 0; n < 4; n++) bv[n] = Ws[tx * 4 + n][kk];
#pragma unroll
            for (int i = 0; i < 4; i++)
#pragma unroll
                for (int n = 0; n < 4; n++)
                    acc[i][n] = fmaf(a[i], bv[n], acc[i][n]);
        }
        __syncthreads();
    }
#pragma unroll
    for (int i = 0; i < 4; i++) {
        int m = m0 + ty * 4 + i;
        int j = j0 + tx * 4;
        if (j < DIP) {
            float4 v = make_float4(acc[i][0], acc[i][1], acc[i][2], acc[i][3]);
            *(float4*)(zx + (size_t)m * DIP + j) = v;
        }
    }
}

// ---------------- Kernel 3: causal depthwise conv(4) + SiLU ----------------
__global__ __launch_bounds__(256) void conv_kernel(const float* __restrict__ zx,
                                                   const float* __restrict__ cw,
                                                   const float* __restrict__ cb,
                                                   float* __restrict__ xBC) {
    int i = blockIdx.x * 256 + threadIdx.x;      // over B*T*CD
    int c = i % CD;
    int t = (i / CD) & (TT - 1);
    int b = i / (CD * TT);
    const float* src = zx + (size_t)b * TT * DIP + DI + c;
    float acc = cb[c];
#pragma unroll
    for (int k = 0; k < 4; k++) {
        int ts = t - 3 + k;
        if (ts >= 0) acc = fmaf(cw[c * 4 + k], src[(size_t)ts * DIP], acc);
    }
    float sg = 1.f / (1.f + expf(-acc));
    xBC[(size_t)i] = acc * sg;
}

// ---------------- Kernel 4: dt softplus + dA ----------------
__global__ __launch_bounds__(256) void dt_kernel(const float* __restrict__ zx,
                                                 const float* __restrict__ dt_bias,
                                                 const float* __restrict__ A_log,
                                                 float* __restrict__ dtv,
                                                 float* __restrict__ dAb) {
    int i = blockIdx.x * 256 + threadIdx.x;     // over B*T*NH
    int hh = i & (NH - 1);
    int m = i >> 5;
    float raw = zx[(size_t)m * DIP + (DI + CD) + hh] + dt_bias[hh];
    float dt = (raw > 20.f) ? raw : log1pf(expf(raw));
    float dA = expf(-expf(A_log[hh]) * dt);
    dtv[i] = dt;
    dAb[i] = dA;
}

// ---------------- Kernel 5: selective scan (depth-8 software pipeline) ----------------
// Grid-limited to 4 waves/CU -> latency must be hidden by ILP: modulo-scheduled
// register queue of depth 8 (all indices compile-time via full unroll).
// ys written into zx cols [2048,4096) (dead after conv+dt).
#define QD 8
__global__ __launch_bounds__(64, 1) void scan_kernel(const float* __restrict__ xBC,
                                                     const float* __restrict__ dAb,
                                                     const float* __restrict__ dtv,
                                                     const float* __restrict__ h0,
                                                     const float* __restrict__ Dp,
                                                     float* __restrict__ zx,
                                                     float* __restrict__ hT) {
    int lane = threadIdx.x;
    int pl = lane >> 4;
    int jg = lane & 15;
    int pc = blockIdx.x, hh = blockIdx.y, b = blockIdx.z;
    int p = pc * 4 + pl;
    int n0 = jg * 8;

    float h[8];
    const float* h0p = h0 + ((size_t)((b * NH + hh) * HD + p)) * DSTATE + n0;
    float4 ha = *(const float4*)h0p;
    float4 hb2 = *(const float4*)(h0p + 4);
    h[0] = ha.x; h[1] = ha.y; h[2] = ha.z; h[3] = ha.w;
    h[4] = hb2.x; h[5] = hb2.y; h[6] = hb2.z; h[7] = hb2.w;

    float Dh = Dp[hh];
    const float* base = xBC + (size_t)b * TT * CD;
    const float* dab = dAb + (size_t)b * TT * NH + hh;
    const float* dtb = dtv + (size_t)b * TT * NH + hh;
    float* yb = zx + (size_t)b * TT * DIP + DI + hh * HD + p;

    float4 qB0[QD], qB1[QD], qC0[QD], qC1[QD];
    float qx[QD], qda[QD], qdt[QD];

#pragma unroll
    for (int j = 0; j < QD; j++) {
        const float* rn = base + (size_t)j * CD;
        qB0[j] = *(const float4*)(rn + DI + n0);
        qB1[j] = *(const float4*)(rn + DI + n0 + 4);
        qC0[j] = *(const float4*)(rn + DI + DSTATE + n0);
        qC1[j] = *(const float4*)(rn + DI + DSTATE + n0 + 4);
        qx[j]  = rn[hh * HD + p];
        qda[j] = dab[(size_t)j * NH];
        qdt[j] = dtb[(size_t)j * NH];
    }

    for (int t = 0; t < TT; t += QD) {
#pragma unroll
        for (int j = 0; j < QD; j++) {
            float xdt = qx[j] * qdt[j];
            float da = qda[j];
            float xin = qx[j];
            float4 B0 = qB0[j], B1 = qB1[j], C0 = qC0[j], C1 = qC1[j];

            // prefetch slot j for time t+j+QD
            int tn = t + j + QD;
            if (tn >= TT) tn = TT - 1;
            const float* rn = base + (size_t)tn * CD;
            qB0[j] = *(const float4*)(rn + DI + n0);
            qB1[j] = *(const float4*)(rn + DI + n0 + 4);
            qC0[j] = *(const float4*)(rn + DI + DSTATE + n0);
            qC1[j] = *(const float4*)(rn + DI + DSTATE + n0 + 4);
            qx[j]  = rn[hh * HD + p];
            qda[j] = dab[(size_t)tn * NH];
            qdt[j] = dtb[(size_t)tn * NH];

            float ps;
            h[0] = fmaf(h[0], da, xdt * B0.x); ps = h[0] * C0.x;
            h[1] = fmaf(h[1], da, xdt * B0.y); ps = fmaf(h[1], C0.y, ps);
            h[2] = fmaf(h[2], da, xdt * B0.z); ps = fmaf(h[2], C0.z, ps);
            h[3] = fmaf(h[3], da, xdt * B0.w); ps = fmaf(h[3], C0.w, ps);
            h[4] = fmaf(h[4], da, xdt * B1.x); ps = fmaf(h[4], C1.x, ps);
            h[5] = fmaf(h[5], da, xdt * B1.y); ps = fmaf(h[5], C1.y, ps);
            h[6] = fmaf(h[6], da, xdt * B1.z); ps = fmaf(h[6], C1.z, ps);
            h[7] = fmaf(h[7], da, xdt * B1.w); ps = fmaf(h[7], C1.w, ps);

            ps += __shfl_xor(ps, 1);
            ps += __shfl_xor(ps, 2);
            ps += __shfl_xor(ps, 4);
            ps += __shfl_xor(ps, 8);
            if (jg == 0) yb[(size_t)(t + j) * DIP] = ps + Dh * xin;
        }
    }
    float* hp = hT + ((size_t)((b * NH + hh) * HD + p)) * DSTATE + n0;
    *(float4*)hp = make_float4(h[0], h[1], h[2], h[3]);
    *(float4*)(hp + 4) = make_float4(h[4], h[5], h[6], h[7]);
}

// ---------------- Kernel 6: gating + RMSNorm (in-place over z cols of zx) ----------------
__global__ __launch_bounds__(256) void gate_rms_kernel(float* __restrict__ zx,
                                                       const float* __restrict__ rw) {
    int m = blockIdx.x;
    int tid = threadIdx.x;
    const float* yr = zx + (size_t)m * DIP + DI;
    float* zr = zx + (size_t)m * DIP;
    float gv[8];
    float ss = 0.f;
#pragma unroll
    for (int i = 0; i < 8; i++) {
        int idx = tid + i * 256;
        float y = yr[idx];
        float z = zr[idx];
        float sg = 1.f / (1.f + expf(-z));
        float gg = y * z * sg;
        gv[i] = gg;
        ss += gg * gg;
    }
#pragma unroll
    for (int off = 1; off < 64; off <<= 1) ss += __shfl_xor(ss, off);
    __shared__ float red[4];
    int w = tid >> 6;
    if ((tid & 63) == 0) red[w] = ss;
    __syncthreads();
    float tot = red[0] + red[1] + red[2] + red[3];
    float r = rsqrtf(tot * (1.f / DI) + 1e-5f);
#pragma unroll
    for (int i = 0; i < 8; i++) {
        int idx = tid + i * 256;
        zr[idx] = gv[i] * r * rw[idx];
    }
}

// ---------------- Kernel 7: GEMM2 (out-proj, transposed store) ----------------
// g lives in zx cols [0,2048) with row stride DIP.
__global__ __launch_bounds__(256) void gemm2_kernel(const float* __restrict__ g,
                                                    const float* __restrict__ Wout,
                                                    float* __restrict__ out) {
    __shared__ float Gs[64][17];
    __shared__ float Ws[64][17];
    int tid = threadIdx.x;
    int tx = tid & 15;    // m-dim
    int ty = tid >> 4;    // n(j)-dim
    int j0 = blockIdx.x * 64;
    int m0 = blockIdx.y * 64;
    int b = m0 >> 12;
    int t0 = m0 & 4095;
    int r = tid >> 2;
    int c = (tid & 3) * 4;
    float acc[4][4] = {};
    for (int k0 = 0; k0 < DI; k0 += 16) {
        float4 gv = *(const float4*)(g + (size_t)(m0 + r) * DIP + k0 + c);
        Gs[r][c] = gv.x; Gs[r][c + 1] = gv.y; Gs[r][c + 2] = gv.z; Gs[r][c + 3] = gv.w;
        float4 wv = *(const float4*)(Wout + (size_t)(j0 + r) * DI + k0 + c);
        Ws[r][c] = wv.x; Ws[r][c + 1] = wv.y; Ws[r][c + 2] = wv.z; Ws[r][c + 3] = wv.w;
        __syncthreads();
#pragma unroll
        for (int kk = 0; kk < 16; kk++) {
            float a[4], bv[4];
#pragma unroll
            for (int i = 0; i < 4; i++) a[i] = Gs[tx * 4 + i][kk];
#pragma unroll
            for (int n = 0; n < 4; n++) bv[n] = Ws[ty * 4 + n][kk];
#pragma unroll
            for (int i = 0; i < 4; i++)
#pragma unroll
                for (int n = 0; n < 4; n++)
                    acc[i][n] = fmaf(a[i], bv[n], acc[i][n]);
        }
        __syncthreads();
    }
#pragma unroll
    for (int n = 0; n < 4; n++) {
        int j = j0 + ty * 4 + n;
        float4 v = make_float4(acc[0][n], acc[1][n], acc[2][n], acc[3][n]);
        *(float4*)(out + (size_t)b * DM * TT + (size_t)j * TT + t0 + tx * 4) = v;
    }
}

extern "C" void kernel_launch(void* const* d_in, const int* in_sizes, int n_in,
                              void* d_out, int out_size, void* d_ws, size_t ws_size,
                              hipStream_t stream) {
    const float* x       = (const float*)d_in[0];
    const float* ln_w    = (const float*)d_in[1];
    const float* ln_b    = (const float*)d_in[2];
    const float* W_in    = (const float*)d_in[3];
    const float* conv_w  = (const float*)d_in[4];
    const float* conv_b  = (const float*)d_in[5];
    const float* dt_bias = (const float*)d_in[6];
    const float* A_log   = (const float*)d_in[7];
    const float* Dp      = (const float*)d_in[8];
    const float* rms_w   = (const float*)d_in[9];
    const float* W_out   = (const float*)d_in[10];
    const float* h0      = (const float*)d_in[11];

    float* out = (float*)d_out;
    float* hT = out + (size_t)BB * DM * TT;

    char* ws = (char*)d_ws;
    // workspace layout (bytes) — total 221,315,072 (~211 MiB):
    float* mu  = (float*)(ws + 0);            //      32,768
    float* rs  = (float*)(ws + 32768);        //      32,768
    float* zx  = (float*)(ws + 65536);        // 143,654,912  (B,T,4384)
    float* xBC = (float*)(ws + 143720448);    //  75,497,472  (B,T,2304)
    float* dAb = (float*)(ws + 219217920);    //   1,048,576  (B,T,32)
    float* dtv = (float*)(ws + 220266496);    //   1,048,576  (B,T,32)

    ln_stats_kernel<<<dim3(TT / 64, BB), 64, 0, stream>>>(x, mu, rs);
    gemm1_kernel<<<dim3((DIP + 63) / 64, (BB * TT) / 64), 256, 0, stream>>>(
        x, mu, rs, ln_w, ln_b, W_in, zx);
    conv_kernel<<<(BB * TT * CD) / 256, 256, 0, stream>>>(zx, conv_w, conv_b, xBC);
    dt_kernel<<<(BB * TT * NH) / 256, 256, 0, stream>>>(zx, dt_bias, A_log, dtv, dAb);
    scan_kernel<<<dim3(16, NH, BB), 64, 0, stream>>>(xBC, dAb, dtv, h0, Dp, zx, hT);
    gate_rms_kernel<<<BB * TT, 256, 0, stream>>>(zx, rms_w);
    gemm2_kernel<<<dim3(DM / 64, (BB * TT) / 64), 256, 0, stream>>>(zx, W_out, out);
}

// Round 4
// 3197.004 us; speedup vs baseline: 1.3159x; 1.2649x over previous
//
#include <hip/hip_runtime.h>
#include <hip/hip_bf16.h>
#include <math.h>

// Problem constants
#define BB 2
#define TT 4096
#define DM 1024
#define DSTATE 128
#define DCONV 4
#define DI 2048
#define HD 64
#define NH 32
#define DIP 4384   // 2*DI + 2*DSTATE + NH
#define CD 2304    // DI + 2*DSTATE

// Chunked scan parameters
#define NC 8
#define CL 512          // chunk length; NC*CL == TT
#define SELEMS ((size_t)BB * NH * HD * DSTATE)   // 524288 elems per chunk slab

// ---------------- Kernel 1: LayerNorm statistics ----------------
__global__ __launch_bounds__(64) void ln_stats_kernel(const float* __restrict__ x,
                                                      float* __restrict__ mu,
                                                      float* __restrict__ rs) {
    int t = blockIdx.x * 64 + threadIdx.x;
    int b = blockIdx.y;
    const float* xb = x + (size_t)b * DM * TT + t;
    float s = 0.f, ss = 0.f;
#pragma unroll 8
    for (int d = 0; d < DM; d++) {
        float v = xb[(size_t)d * TT];
        s += v;
        ss += v * v;
    }
    float m = s * (1.f / DM);
    float var = ss * (1.f / DM) - m * m;
    int idx = b * TT + t;
    mu[idx] = m;
    rs[idx] = rsqrtf(var + 1e-5f);
}

// ---------------- Kernel 2: GEMM1 with fused LayerNorm affine ----------------
__global__ __launch_bounds__(256) void gemm1_kernel(const float* __restrict__ x,
                                                    const float* __restrict__ mu,
                                                    const float* __restrict__ rs,
                                                    const float* __restrict__ ln_w,
                                                    const float* __restrict__ ln_b,
                                                    const float* __restrict__ Win,
                                                    float* __restrict__ zx) {
    __shared__ float As[16][64];      // [k][m] tile
    __shared__ float Ws[64][17];      // [j][k] tile (padded)
    int tid = threadIdx.x;
    int tx = tid & 15;    // n(j)-dim
    int ty = tid >> 4;    // m-dim
    int j0 = blockIdx.x * 64;
    int m0 = blockIdx.y * 64;
    int b = m0 >> 12;
    int t0 = m0 & 4095;
    const float* Xb = x + (size_t)b * DM * TT + t0;

    int lr = tid >> 4;
    int lc = (tid & 15) * 4;
    int wr = tid >> 2;
    int wc = (tid & 3) * 4;

    float acc[4][4] = {};
    for (int k0 = 0; k0 < DM; k0 += 16) {
        float4 xv = *(const float4*)(Xb + (size_t)(k0 + lr) * TT + lc);
        float4 muv = *(const float4*)(&mu[m0 + lc]);
        float4 rsv = *(const float4*)(&rs[m0 + lc]);
        float lw = ln_w[k0 + lr], lb = ln_b[k0 + lr];
        As[lr][lc]     = (xv.x - muv.x) * rsv.x * lw + lb;
        As[lr][lc + 1] = (xv.y - muv.y) * rsv.y * lw + lb;
        As[lr][lc + 2] = (xv.z - muv.z) * rsv.z * lw + lb;
        As[lr][lc + 3] = (xv.w - muv.w) * rsv.w * lw + lb;

        int j = j0 + wr;
        float4 wv = make_float4(0.f, 0.f, 0.f, 0.f);
        if (j < DIP) wv = *(const float4*)(Win + (size_t)j * DM + k0 + wc);
        Ws[wr][wc] = wv.x; Ws[wr][wc + 1] = wv.y; Ws[wr][wc + 2] = wv.z; Ws[wr][wc + 3] = wv.w;
        __syncthreads();
#pragma unroll
        for (int kk = 0; kk < 16; kk++) {
            float4 a4 = *(const float4*)&As[kk][ty * 4];
            float a[4] = {a4.x, a4.y, a4.z, a4.w};
            float bv[4];
#pragma unroll
            for (int n = 0; n < 4; n++) bv[n] = Ws[tx * 4 + n][kk];
#pragma unroll
            for (int i = 0; i < 4; i++)
#pragma unroll
                for (int n = 0; n < 4; n++)
                    acc[i][n] = fmaf(a[i], bv[n], acc[i][n]);
        }
        __syncthreads();
    }
#pragma unroll
    for (int i = 0; i < 4; i++) {
        int m = m0 + ty * 4 + i;
        int j = j0 + tx * 4;
        if (j < DIP) {
            float4 v = make_float4(acc[i][0], acc[i][1], acc[i][2], acc[i][3]);
            *(float4*)(zx + (size_t)m * DIP + j) = v;
        }
    }
}

// ---------------- Kernel 3: causal depthwise conv(4) + SiLU ----------------
__global__ __launch_bounds__(256) void conv_kernel(const float* __restrict__ zx,
                                                   const float* __restrict__ cw,
                                                   const float* __restrict__ cb,
                                                   float* __restrict__ xBC) {
    int i = blockIdx.x * 256 + threadIdx.x;
    int c = i % CD;
    int t = (i / CD) & (TT - 1);
    int b = i / (CD * TT);
    const float* src = zx + (size_t)b * TT * DIP + DI + c;
    float acc = cb[c];
#pragma unroll
    for (int k = 0; k < 4; k++) {
        int ts = t - 3 + k;
        if (ts >= 0) acc = fmaf(cw[c * 4 + k], src[(size_t)ts * DIP], acc);
    }
    float sg = 1.f / (1.f + expf(-acc));
    xBC[(size_t)i] = acc * sg;
}

// ---------------- Kernel 4: dt softplus + dA ----------------
__global__ __launch_bounds__(256) void dt_kernel(const float* __restrict__ zx,
                                                 const float* __restrict__ dt_bias,
                                                 const float* __restrict__ A_log,
                                                 float* __restrict__ dtv,
                                                 float* __restrict__ dAb) {
    int i = blockIdx.x * 256 + threadIdx.x;
    int hh = i & (NH - 1);
    int m = i >> 5;
    float raw = zx[(size_t)m * DIP + (DI + CD) + hh] + dt_bias[hh];
    float dt = (raw > 20.f) ? raw : log1pf(expf(raw));
    float dA = expf(-expf(A_log[hh]) * dt);
    dtv[i] = dt;
    dAb[i] = dA;
}

// ---------------- Kernel 5a: chunk reduce (local scan from zero; store S_c, P_c) ----------------
// grid: (16*NC, NH, BB), 64 threads. lane = pl*16+jg, p = pc*4+pl, n = jg*8..+8.
__global__ __launch_bounds__(64) void scan_reduce_kernel(const float* __restrict__ xBC,
                                                         const float* __restrict__ dAb,
                                                         const float* __restrict__ dtv,
                                                         float* __restrict__ S,
                                                         float* __restrict__ P) {
    int lane = threadIdx.x;
    int pl = lane >> 4;
    int jg = lane & 15;
    int pc = blockIdx.x & 15;
    int c = blockIdx.x >> 4;
    int hh = blockIdx.y, b = blockIdx.z;
    int p = pc * 4 + pl;
    int n0 = jg * 8;
    int tbeg = c * CL;

    float h[8] = {};
    float cd = 1.f;

    const float* base = xBC + (size_t)b * TT * CD;
    const float* dab = dAb + (size_t)b * TT * NH + hh;
    const float* dtb = dtv + (size_t)b * TT * NH + hh;

    const float* r0 = base + (size_t)tbeg * CD;
    float4 B0 = *(const float4*)(r0 + DI + n0);
    float4 B1 = *(const float4*)(r0 + DI + n0 + 4);
    float xin = r0[hh * HD + p];
    float da = dab[(size_t)tbeg * NH];
    float dt = dtb[(size_t)tbeg * NH];

    for (int t = tbeg; t < tbeg + CL; t++) {
        int tn = (t + 1 < tbeg + CL) ? (t + 1) : t;
        const float* rn = base + (size_t)tn * CD;
        float4 nB0 = *(const float4*)(rn + DI + n0);
        float4 nB1 = *(const float4*)(rn + DI + n0 + 4);
        float nx = rn[hh * HD + p];
        float nda = dab[(size_t)tn * NH];
        float ndt = dtb[(size_t)tn * NH];

        float xdt = xin * dt;
        h[0] = fmaf(h[0], da, xdt * B0.x);
        h[1] = fmaf(h[1], da, xdt * B0.y);
        h[2] = fmaf(h[2], da, xdt * B0.z);
        h[3] = fmaf(h[3], da, xdt * B0.w);
        h[4] = fmaf(h[4], da, xdt * B1.x);
        h[5] = fmaf(h[5], da, xdt * B1.y);
        h[6] = fmaf(h[6], da, xdt * B1.z);
        h[7] = fmaf(h[7], da, xdt * B1.w);
        cd *= da;

        B0 = nB0; B1 = nB1; xin = nx; da = nda; dt = ndt;
    }

    float* Sp = S + (size_t)c * SELEMS + (((size_t)(b * NH + hh) * HD + p) * DSTATE) + n0;
    *(float4*)Sp = make_float4(h[0], h[1], h[2], h[3]);
    *(float4*)(Sp + 4) = make_float4(h[4], h[5], h[6], h[7]);
    if (lane == 0) P[(c * BB + b) * NH + hh] = cd;
}

// ---------------- Kernel 5b: sequential chunk combine; S[c] := h_in[c]; emits hT ----------------
__global__ __launch_bounds__(256) void scan_combine_kernel(const float* __restrict__ h0,
                                                           const float* __restrict__ P,
                                                           float* __restrict__ S,
                                                           float* __restrict__ hT) {
    size_t tid = (size_t)blockIdx.x * 256 + threadIdx.x;   // over SELEMS
    int hh = (int)((tid >> 13) & 31);
    int b = (int)(tid >> 18);
    float h = h0[tid];
#pragma unroll
    for (int c = 0; c < NC; c++) {
        float s = S[(size_t)c * SELEMS + tid];
        S[(size_t)c * SELEMS + tid] = h;
        h = fmaf(P[(c * BB + b) * NH + hh], h, s);
    }
    hT[tid] = h;
}

// ---------------- Kernel 5c: chunk emit (scan from h_in[c], write y) ----------------
// y written into zx cols [2048,4096) (dead after conv+dt).
__global__ __launch_bounds__(64) void scan_emit_kernel(const float* __restrict__ xBC,
                                                       const float* __restrict__ dAb,
                                                       const float* __restrict__ dtv,
                                                       const float* __restrict__ S,
                                                       const float* __restrict__ Dp,
                                                       float* __restrict__ zx) {
    int lane = threadIdx.x;
    int pl = lane >> 4;
    int jg = lane & 15;
    int pc = blockIdx.x & 15;
    int c = blockIdx.x >> 4;
    int hh = blockIdx.y, b = blockIdx.z;
    int p = pc * 4 + pl;
    int n0 = jg * 8;
    int tbeg = c * CL;

    const float* Sp = S + (size_t)c * SELEMS + (((size_t)(b * NH + hh) * HD + p) * DSTATE) + n0;
    float4 ha = *(const float4*)Sp;
    float4 hb2 = *(const float4*)(Sp + 4);
    float h[8] = {ha.x, ha.y, ha.z, ha.w, hb2.x, hb2.y, hb2.z, hb2.w};

    float Dh = Dp[hh];
    const float* base = xBC + (size_t)b * TT * CD;
    const float* dab = dAb + (size_t)b * TT * NH + hh;
    const float* dtb = dtv + (size_t)b * TT * NH + hh;
    float* yb = zx + (size_t)b * TT * DIP + DI + hh * HD + p;

    const float* r0 = base + (size_t)tbeg * CD;
    float4 B0 = *(const float4*)(r0 + DI + n0);
    float4 B1 = *(const float4*)(r0 + DI + n0 + 4);
    float4 C0 = *(const float4*)(r0 + DI + DSTATE + n0);
    float4 C1 = *(const float4*)(r0 + DI + DSTATE + n0 + 4);
    float xin = r0[hh * HD + p];
    float da = dab[(size_t)tbeg * NH];
    float dt = dtb[(size_t)tbeg * NH];

    for (int t = tbeg; t < tbeg + CL; t++) {
        int tn = (t + 1 < tbeg + CL) ? (t + 1) : t;
        const float* rn = base + (size_t)tn * CD;
        float4 nB0 = *(const float4*)(rn + DI + n0);
        float4 nB1 = *(const float4*)(rn + DI + n0 + 4);
        float4 nC0 = *(const float4*)(rn + DI + DSTATE + n0);
        float4 nC1 = *(const float4*)(rn + DI + DSTATE + n0 + 4);
        float nx = rn[hh * HD + p];
        float nda = dab[(size_t)tn * NH];
        float ndt = dtb[(size_t)tn * NH];

        float xdt = xin * dt;
        float ps;
        h[0] = fmaf(h[0], da, xdt * B0.x); ps = h[0] * C0.x;
        h[1] = fmaf(h[1], da, xdt * B0.y); ps = fmaf(h[1], C0.y, ps);
        h[2] = fmaf(h[2], da, xdt * B0.z); ps = fmaf(h[2], C0.z, ps);
        h[3] = fmaf(h[3], da, xdt * B0.w); ps = fmaf(h[3], C0.w, ps);
        h[4] = fmaf(h[4], da, xdt * B1.x); ps = fmaf(h[4], C1.x, ps);
        h[5] = fmaf(h[5], da, xdt * B1.y); ps = fmaf(h[5], C1.y, ps);
        h[6] = fmaf(h[6], da, xdt * B1.z); ps = fmaf(h[6], C1.z, ps);
        h[7] = fmaf(h[7], da, xdt * B1.w); ps = fmaf(h[7], C1.w, ps);

        ps += __shfl_xor(ps, 1);
        ps += __shfl_xor(ps, 2);
        ps += __shfl_xor(ps, 4);
        ps += __shfl_xor(ps, 8);
        if (jg == 0) yb[(size_t)t * DIP] = ps + Dh * xin;

        B0 = nB0; B1 = nB1; C0 = nC0; C1 = nC1;
        xin = nx; da = nda; dt = ndt;
    }
}

// ---------------- Kernel 6: gating + RMSNorm (in-place over z cols of zx) ----------------
__global__ __launch_bounds__(256) void gate_rms_kernel(float* __restrict__ zx,
                                                       const float* __restrict__ rw) {
    int m = blockIdx.x;
    int tid = threadIdx.x;
    const float* yr = zx + (size_t)m * DIP + DI;
    float* zr = zx + (size_t)m * DIP;
    float gv[8];
    float ss = 0.f;
#pragma unroll
    for (int i = 0; i < 8; i++) {
        int idx = tid + i * 256;
        float y = yr[idx];
        float z = zr[idx];
        float sg = 1.f / (1.f + expf(-z));
        float gg = y * z * sg;
        gv[i] = gg;
        ss += gg * gg;
    }
#pragma unroll
    for (int off = 1; off < 64; off <<= 1) ss += __shfl_xor(ss, off);
    __shared__ float red[4];
    int w = tid >> 6;
    if ((tid & 63) == 0) red[w] = ss;
    __syncthreads();
    float tot = red[0] + red[1] + red[2] + red[3];
    float r = rsqrtf(tot * (1.f / DI) + 1e-5f);
#pragma unroll
    for (int i = 0; i < 8; i++) {
        int idx = tid + i * 256;
        zr[idx] = gv[i] * r * rw[idx];
    }
}

// ---------------- Kernel 7: GEMM2 (out-proj, transposed store) ----------------
__global__ __launch_bounds__(256) void gemm2_kernel(const float* __restrict__ g,
                                                    const float* __restrict__ Wout,
                                                    float* __restrict__ out) {
    __shared__ float Gs[64][17];
    __shared__ float Ws[64][17];
    int tid = threadIdx.x;
    int tx = tid & 15;    // m-dim
    int ty = tid >> 4;    // n(j)-dim
    int j0 = blockIdx.x * 64;
    int m0 = blockIdx.y * 64;
    int b = m0 >> 12;
    int t0 = m0 & 4095;
    int r = tid >> 2;
    int c = (tid & 3) * 4;
    float acc[4][4] = {};
    for (int k0 = 0; k0 < DI; k0 += 16) {
        float4 gv = *(const float4*)(g + (size_t)(m0 + r) * DIP + k0 + c);
        Gs[r][c] = gv.x; Gs[r][c + 1] = gv.y; Gs[r][c + 2] = gv.z; Gs[r][c + 3] = gv.w;
        float4 wv = *(const float4*)(Wout + (size_t)(j0 + r) * DI + k0 + c);
        Ws[r][c] = wv.x; Ws[r][c + 1] = wv.y; Ws[r][c + 2] = wv.z; Ws[r][c + 3] = wv.w;
        __syncthreads();
#pragma unroll
        for (int kk = 0; kk < 16; kk++) {
            float a[4], bv[4];
#pragma unroll
            for (int i = 0; i < 4; i++) a[i] = Gs[tx * 4 + i][kk];
#pragma unroll
            for (int n = 0; n < 4; n++) bv[n] = Ws[ty * 4 + n][kk];
#pragma unroll
            for (int i = 0; i < 4; i++)
#pragma unroll
                for (int n = 0; n < 4; n++)
                    acc[i][n] = fmaf(a[i], bv[n], acc[i][n]);
        }
        __syncthreads();
    }
#pragma unroll
    for (int n = 0; n < 4; n++) {
        int j = j0 + ty * 4 + n;
        float4 v = make_float4(acc[0][n], acc[1][n], acc[2][n], acc[3][n]);
        *(float4*)(out + (size_t)b * DM * TT + (size_t)j * TT + t0 + tx * 4) = v;
    }
}

extern "C" void kernel_launch(void* const* d_in, const int* in_sizes, int n_in,
                              void* d_out, int out_size, void* d_ws, size_t ws_size,
                              hipStream_t stream) {
    const float* x       = (const float*)d_in[0];
    const float* ln_w    = (const float*)d_in[1];
    const float* ln_b    = (const float*)d_in[2];
    const float* W_in    = (const float*)d_in[3];
    const float* conv_w  = (const float*)d_in[4];
    const float* conv_b  = (const float*)d_in[5];
    const float* dt_bias = (const float*)d_in[6];
    const float* A_log   = (const float*)d_in[7];
    const float* Dp      = (const float*)d_in[8];
    const float* rms_w   = (const float*)d_in[9];
    const float* W_out   = (const float*)d_in[10];
    const float* h0      = (const float*)d_in[11];

    float* out = (float*)d_out;
    float* hT = out + (size_t)BB * DM * TT;

    char* ws = (char*)d_ws;
    // workspace layout (bytes) — total 238,096,384 (~227 MiB):
    float* mu  = (float*)(ws + 0);            //      32,768
    float* rs  = (float*)(ws + 32768);        //      32,768
    float* zx  = (float*)(ws + 65536);        // 143,654,912  (B,T,4384)
    float* xBC = (float*)(ws + 143720448);    //  75,497,472  (B,T,2304)
    float* dAb = (float*)(ws + 219217920);    //   1,048,576  (B,T,32)
    float* dtv = (float*)(ws + 220266496);    //   1,048,576  (B,T,32)
    float* S   = (float*)(ws + 221315072);    //  16,777,216  (NC slabs of 524288 f)
    float* P   = (float*)(ws + 238092288);    //       2,048  (NC,B,NH)

    ln_stats_kernel<<<dim3(TT / 64, BB), 64, 0, stream>>>(x, mu, rs);
    gemm1_kernel<<<dim3((DIP + 63) / 64, (BB * TT) / 64), 256, 0, stream>>>(
        x, mu, rs, ln_w, ln_b, W_in, zx);
    conv_kernel<<<(BB * TT * CD) / 256, 256, 0, stream>>>(zx, conv_w, conv_b, xBC);
    dt_kernel<<<(BB * TT * NH) / 256, 256, 0, stream>>>(zx, dt_bias, A_log, dtv, dAb);
    scan_reduce_kernel<<<dim3(16 * NC, NH, BB), 64, 0, stream>>>(xBC, dAb, dtv, S, P);
    scan_combine_kernel<<<(int)(SELEMS / 256), 256, 0, stream>>>(h0, P, S, hT);
    scan_emit_kernel<<<dim3(16 * NC, NH, BB), 64, 0, stream>>>(xBC, dAb, dtv, S, Dp, zx);
    gate_rms_kernel<<<BB * TT, 256, 0, stream>>>(zx, rms_w);
    gemm2_kernel<<<dim3(DM / 64, (BB * TT) / 64), 256, 0, stream>>>(zx, W_out, out);
}

// Round 5
// 1457.891 us; speedup vs baseline: 2.8856x; 2.1929x over previous
//
#include <hip/hip_runtime.h>
#include <hip/hip_bf16.h>
#include <math.h>

// Problem constants
#define BB 2
#define TT 4096
#define DM 1024
#define DSTATE 128
#define DI 2048
#define HD 64
#define NH 32
#define DIP 4384   // 2*DI + 2*DSTATE + NH
#define CD 2304    // DI + 2*DSTATE

// Chunked scan parameters
#define NC 8
#define CL 512
#define SELEMS ((size_t)BB * NH * HD * DSTATE)   // 524288

#define NP1 4480   // DIP padded to multiple of 128 for MFMA staging

typedef __attribute__((ext_vector_type(8))) short bf16x8;
typedef __attribute__((ext_vector_type(4))) float f32x4;

__device__ inline void gload16(const void* g, void* l) {
    __builtin_amdgcn_global_load_lds(
        (const __attribute__((address_space(1))) void*)g,
        (__attribute__((address_space(3))) void*)l, 16, 0, 0);
}

// ---------------- Kernel 1: LayerNorm statistics ----------------
__global__ __launch_bounds__(64) void ln_stats_kernel(const float* __restrict__ x,
                                                      float* __restrict__ mu,
                                                      float* __restrict__ rs) {
    int t = blockIdx.x * 64 + threadIdx.x;
    int b = blockIdx.y;
    const float* xb = x + (size_t)b * DM * TT + t;
    float s = 0.f, ss = 0.f;
#pragma unroll 8
    for (int d = 0; d < DM; d++) {
        float v = xb[(size_t)d * TT];
        s += v;
        ss += v * v;
    }
    float m = s * (1.f / DM);
    float var = ss * (1.f / DM) - m * m;
    int idx = b * TT + t;
    mu[idx] = m;
    rs[idx] = rsqrtf(var + 1e-5f);
}

// ---------------- Kernel 1b: xn = LN(x) transposed to (m, k) in bf16 ----------------
__global__ __launch_bounds__(256) void xn_kernel(const float* __restrict__ x,
                                                 const float* __restrict__ mu,
                                                 const float* __restrict__ rs,
                                                 const float* __restrict__ ln_w,
                                                 const float* __restrict__ ln_b,
                                                 __hip_bfloat16* __restrict__ xn) {
    __shared__ float tile[64][65];
    int tid = threadIdx.x;
    int t0 = blockIdx.x * 64, d0 = blockIdx.y * 64, b = blockIdx.z;
#pragma unroll
    for (int i = 0; i < 64; i += 4) {
        int dl = i + (tid >> 6);
        tile[dl][tid & 63] = x[(size_t)b * DM * TT + (size_t)(d0 + dl) * TT + t0 + (tid & 63)];
    }
    __syncthreads();
#pragma unroll
    for (int i = 0; i < 64; i += 8) {
        int tl = i + (tid >> 5);
        int kk = (tid & 31) * 2;
        int m = b * TT + t0 + tl;
        float mu_m = mu[m], rs_m = rs[m];
        float v0 = (tile[kk][tl] - mu_m) * rs_m * ln_w[d0 + kk] + ln_b[d0 + kk];
        float v1 = (tile[kk + 1][tl] - mu_m) * rs_m * ln_w[d0 + kk + 1] + ln_b[d0 + kk + 1];
        __hip_bfloat162 pk;
        pk.x = __float2bfloat16(v0);
        pk.y = __float2bfloat16(v1);
        *(__hip_bfloat162*)(xn + (size_t)m * DM + d0 + kk) = pk;
    }
}

// ---------------- convert f32 -> bf16 with zero-padding ----------------
__global__ __launch_bounds__(256) void cvt_pad_kernel(const float* __restrict__ src,
                                                      __hip_bfloat16* __restrict__ dst,
                                                      int src_n, int tot_n) {
    int i = (blockIdx.x * 256 + threadIdx.x) * 4;
    if (i >= tot_n) return;
    float4 v = (i < src_n) ? *(const float4*)(src + i) : make_float4(0.f, 0.f, 0.f, 0.f);
    __hip_bfloat162 p0, p1;
    p0.x = __float2bfloat16(v.x); p0.y = __float2bfloat16(v.y);
    p1.x = __float2bfloat16(v.z); p1.y = __float2bfloat16(v.w);
    *(__hip_bfloat162*)(dst + i) = p0;
    *(__hip_bfloat162*)(dst + i + 2) = p1;
}

// ---------------- Kernel 2: GEMM1 bf16 MFMA (m97 structure) ----------------
// D[j][m] = sum_k Wb[j][k] * xn[m][k].  Store float4 along j into zx[m*DIP + j].
__global__ __launch_bounds__(256) void gemm1_mfma(const __hip_bfloat16* __restrict__ Wb,
                                                  const __hip_bfloat16* __restrict__ xn,
                                                  float* __restrict__ zx) {
    __shared__ short As[128][64];   // W rows (j), k-contiguous
    __shared__ short Bs[128][64];   // xn rows (m), k-contiguous
    int tid = threadIdx.x;
    int lane = tid & 63;
    int wave = tid >> 6;
    int wr = wave >> 1, wc = wave & 1;
    int j0 = blockIdx.x * 128;
    int m0 = blockIdx.y * 128;
    int srow = tid >> 3;          // 0..31
    int skc = (tid & 7) * 8;      // k element offset

    f32x4 acc[4][4] = {};

    for (int k0 = 0; k0 < DM; k0 += 64) {
        __syncthreads();
#pragma unroll
        for (int q = 0; q < 4; q++) {
            gload16(Wb + (size_t)(j0 + q * 32 + srow) * DM + k0 + skc,
                    ((short*)As) + q * 2048 + wave * 512);
            gload16(xn + (size_t)(m0 + q * 32 + srow) * DM + k0 + skc,
                    ((short*)Bs) + q * 2048 + wave * 512);
        }
        asm volatile("s_waitcnt vmcnt(0)" ::: "memory");
        __syncthreads();
#pragma unroll
        for (int ks = 0; ks < 2; ks++) {
            bf16x8 af[4], bfr[4];
#pragma unroll
            for (int i = 0; i < 4; i++)
                af[i] = *(const bf16x8*)&As[wr * 64 + i * 16 + (lane & 15)][ks * 32 + (lane >> 4) * 8];
#pragma unroll
            for (int n = 0; n < 4; n++)
                bfr[n] = *(const bf16x8*)&Bs[wc * 64 + n * 16 + (lane & 15)][ks * 32 + (lane >> 4) * 8];
#pragma unroll
            for (int i = 0; i < 4; i++)
#pragma unroll
                for (int n = 0; n < 4; n++)
                    acc[i][n] = __builtin_amdgcn_mfma_f32_16x16x32_bf16(af[i], bfr[n], acc[i][n], 0, 0, 0);
        }
    }
#pragma unroll
    for (int i = 0; i < 4; i++) {
        int j = j0 + wr * 64 + i * 16 + ((lane >> 4) << 2);
        if (j < DIP) {
#pragma unroll
            for (int n = 0; n < 4; n++) {
                int m = m0 + wc * 64 + n * 16 + (lane & 15);
                *(f32x4*)(zx + (size_t)m * DIP + j) = acc[i][n];
            }
        }
    }
}

// ---------------- Kernel 2b: f32 strip GEMM for dt columns (j in [4352,4384)) ----------------
__global__ __launch_bounds__(256) void gemm1_kernel(const float* __restrict__ x,
                                                    const float* __restrict__ mu,
                                                    const float* __restrict__ rs,
                                                    const float* __restrict__ ln_w,
                                                    const float* __restrict__ ln_b,
                                                    const float* __restrict__ Win,
                                                    float* __restrict__ zx,
                                                    int jbase) {
    __shared__ float As[16][64];
    __shared__ float Ws[64][17];
    int tid = threadIdx.x;
    int tx = tid & 15;
    int ty = tid >> 4;
    int j0 = jbase + blockIdx.x * 64;
    int m0 = blockIdx.y * 64;
    int b = m0 >> 12;
    int t0 = m0 & 4095;
    const float* Xb = x + (size_t)b * DM * TT + t0;

    int lr = tid >> 4;
    int lc = (tid & 15) * 4;
    int wr = tid >> 2;
    int wc = (tid & 3) * 4;

    float acc[4][4] = {};
    for (int k0 = 0; k0 < DM; k0 += 16) {
        float4 xv = *(const float4*)(Xb + (size_t)(k0 + lr) * TT + lc);
        float4 muv = *(const float4*)(&mu[m0 + lc]);
        float4 rsv = *(const float4*)(&rs[m0 + lc]);
        float lw = ln_w[k0 + lr], lb = ln_b[k0 + lr];
        As[lr][lc]     = (xv.x - muv.x) * rsv.x * lw + lb;
        As[lr][lc + 1] = (xv.y - muv.y) * rsv.y * lw + lb;
        As[lr][lc + 2] = (xv.z - muv.z) * rsv.z * lw + lb;
        As[lr][lc + 3] = (xv.w - muv.w) * rsv.w * lw + lb;

        int j = j0 + wr;
        float4 wv = make_float4(0.f, 0.f, 0.f, 0.f);
        if (j < DIP) wv = *(const float4*)(Win + (size_t)j * DM + k0 + wc);
        Ws[wr][wc] = wv.x; Ws[wr][wc + 1] = wv.y; Ws[wr][wc + 2] = wv.z; Ws[wr][wc + 3] = wv.w;
        __syncthreads();
#pragma unroll
        for (int kk = 0; kk < 16; kk++) {
            float4 a4 = *(const float4*)&As[kk][ty * 4];
            float a[4] = {a4.x, a4.y, a4.z, a4.w};
            float bv[4];
#pragma unroll
            for (int n = 0; n < 4; n++) bv[n] = Ws[tx * 4 + n][kk];
#pragma unroll
            for (int i = 0; i < 4; i++)
#pragma unroll
                for (int n = 0; n < 4; n++)
                    acc[i][n] = fmaf(a[i], bv[n], acc[i][n]);
        }
        __syncthreads();
    }
#pragma unroll
    for (int i = 0; i < 4; i++) {
        int m = m0 + ty * 4 + i;
        int j = j0 + tx * 4;
        if (j < DIP) {
            float4 v = make_float4(acc[i][0], acc[i][1], acc[i][2], acc[i][3]);
            *(float4*)(zx + (size_t)m * DIP + j) = v;
        }
    }
}

// ---------------- Kernel 3: causal depthwise conv(4) + SiLU ----------------
__global__ __launch_bounds__(256) void conv_kernel(const float* __restrict__ zx,
                                                   const float* __restrict__ cw,
                                                   const float* __restrict__ cb,
                                                   float* __restrict__ xBC) {
    int i = blockIdx.x * 256 + threadIdx.x;
    int c = i % CD;
    int t = (i / CD) & (TT - 1);
    int b = i / (CD * TT);
    const float* src = zx + (size_t)b * TT * DIP + DI + c;
    float acc = cb[c];
#pragma unroll
    for (int k = 0; k < 4; k++) {
        int ts = t - 3 + k;
        if (ts >= 0) acc = fmaf(cw[c * 4 + k], src[(size_t)ts * DIP], acc);
    }
    float sg = 1.f / (1.f + expf(-acc));
    xBC[(size_t)i] = acc * sg;
}

// ---------------- Kernel 4: dt softplus + dA ----------------
__global__ __launch_bounds__(256) void dt_kernel(const float* __restrict__ zx,
                                                 const float* __restrict__ dt_bias,
                                                 const float* __restrict__ A_log,
                                                 float* __restrict__ dtv,
                                                 float* __restrict__ dAb) {
    int i = blockIdx.x * 256 + threadIdx.x;
    int hh = i & (NH - 1);
    int m = i >> 5;
    float raw = zx[(size_t)m * DIP + (DI + CD) + hh] + dt_bias[hh];
    float dt = (raw > 20.f) ? raw : log1pf(expf(raw));
    float dA = expf(-expf(A_log[hh]) * dt);
    dtv[i] = dt;
    dAb[i] = dA;
}

// ---------------- Kernel 5a: chunk reduce ----------------
__global__ __launch_bounds__(64) void scan_reduce_kernel(const float* __restrict__ xBC,
                                                         const float* __restrict__ dAb,
                                                         const float* __restrict__ dtv,
                                                         float* __restrict__ S,
                                                         float* __restrict__ P) {
    int lane = threadIdx.x;
    int pl = lane >> 4;
    int jg = lane & 15;
    int pc = blockIdx.x & 15;
    int c = blockIdx.x >> 4;
    int hh = blockIdx.y, b = blockIdx.z;
    int p = pc * 4 + pl;
    int n0 = jg * 8;
    int tbeg = c * CL;

    float h[8] = {};
    float cd = 1.f;

    const float* base = xBC + (size_t)b * TT * CD;
    const float* dab = dAb + (size_t)b * TT * NH + hh;
    const float* dtb = dtv + (size_t)b * TT * NH + hh;

    const float* r0 = base + (size_t)tbeg * CD;
    float4 B0 = *(const float4*)(r0 + DI + n0);
    float4 B1 = *(const float4*)(r0 + DI + n0 + 4);
    float xin = r0[hh * HD + p];
    float da = dab[(size_t)tbeg * NH];
    float dt = dtb[(size_t)tbeg * NH];

    for (int t = tbeg; t < tbeg + CL; t++) {
        int tn = (t + 1 < tbeg + CL) ? (t + 1) : t;
        const float* rn = base + (size_t)tn * CD;
        float4 nB0 = *(const float4*)(rn + DI + n0);
        float4 nB1 = *(const float4*)(rn + DI + n0 + 4);
        float nx = rn[hh * HD + p];
        float nda = dab[(size_t)tn * NH];
        float ndt = dtb[(size_t)tn * NH];

        float xdt = xin * dt;
        h[0] = fmaf(h[0], da, xdt * B0.x);
        h[1] = fmaf(h[1], da, xdt * B0.y);
        h[2] = fmaf(h[2], da, xdt * B0.z);
        h[3] = fmaf(h[3], da, xdt * B0.w);
        h[4] = fmaf(h[4], da, xdt * B1.x);
        h[5] = fmaf(h[5], da, xdt * B1.y);
        h[6] = fmaf(h[6], da, xdt * B1.z);
        h[7] = fmaf(h[7], da, xdt * B1.w);
        cd *= da;

        B0 = nB0; B1 = nB1; xin = nx; da = nda; dt = ndt;
    }

    float* Sp = S + (size_t)c * SELEMS + (((size_t)(b * NH + hh) * HD + p) * DSTATE) + n0;
    *(float4*)Sp = make_float4(h[0], h[1], h[2], h[3]);
    *(float4*)(Sp + 4) = make_float4(h[4], h[5], h[6], h[7]);
    if (lane == 0) P[(c * BB + b) * NH + hh] = cd;
}

// ---------------- Kernel 5b: sequential chunk combine ----------------
__global__ __launch_bounds__(256) void scan_combine_kernel(const float* __restrict__ h0,
                                                           const float* __restrict__ P,
                                                           float* __restrict__ S,
                                                           float* __restrict__ hT) {
    size_t tid = (size_t)blockIdx.x * 256 + threadIdx.x;
    int hh = (int)((tid >> 13) & 31);
    int b = (int)(tid >> 18);
    float h = h0[tid];
#pragma unroll
    for (int c = 0; c < NC; c++) {
        float s = S[(size_t)c * SELEMS + tid];
        S[(size_t)c * SELEMS + tid] = h;
        h = fmaf(P[(c * BB + b) * NH + hh], h, s);
    }
    hT[tid] = h;
}

// ---------------- Kernel 5c: chunk emit ----------------
__global__ __launch_bounds__(64) void scan_emit_kernel(const float* __restrict__ xBC,
                                                       const float* __restrict__ dAb,
                                                       const float* __restrict__ dtv,
                                                       const float* __restrict__ S,
                                                       const float* __restrict__ Dp,
                                                       float* __restrict__ zx) {
    int lane = threadIdx.x;
    int pl = lane >> 4;
    int jg = lane & 15;
    int pc = blockIdx.x & 15;
    int c = blockIdx.x >> 4;
    int hh = blockIdx.y, b = blockIdx.z;
    int p = pc * 4 + pl;
    int n0 = jg * 8;
    int tbeg = c * CL;

    const float* Sp = S + (size_t)c * SELEMS + (((size_t)(b * NH + hh) * HD + p) * DSTATE) + n0;
    float4 ha = *(const float4*)Sp;
    float4 hb2 = *(const float4*)(Sp + 4);
    float h[8] = {ha.x, ha.y, ha.z, ha.w, hb2.x, hb2.y, hb2.z, hb2.w};

    float Dh = Dp[hh];
    const float* base = xBC + (size_t)b * TT * CD;
    const float* dab = dAb + (size_t)b * TT * NH + hh;
    const float* dtb = dtv + (size_t)b * TT * NH + hh;
    float* yb = zx + (size_t)b * TT * DIP + DI + hh * HD + p;

    const float* r0 = base + (size_t)tbeg * CD;
    float4 B0 = *(const float4*)(r0 + DI + n0);
    float4 B1 = *(const float4*)(r0 + DI + n0 + 4);
    float4 C0 = *(const float4*)(r0 + DI + DSTATE + n0);
    float4 C1 = *(const float4*)(r0 + DI + DSTATE + n0 + 4);
    float xin = r0[hh * HD + p];
    float da = dab[(size_t)tbeg * NH];
    float dt = dtb[(size_t)tbeg * NH];

    for (int t = tbeg; t < tbeg + CL; t++) {
        int tn = (t + 1 < tbeg + CL) ? (t + 1) : t;
        const float* rn = base + (size_t)tn * CD;
        float4 nB0 = *(const float4*)(rn + DI + n0);
        float4 nB1 = *(const float4*)(rn + DI + n0 + 4);
        float4 nC0 = *(const float4*)(rn + DI + DSTATE + n0);
        float4 nC1 = *(const float4*)(rn + DI + DSTATE + n0 + 4);
        float nx = rn[hh * HD + p];
        float nda = dab[(size_t)tn * NH];
        float ndt = dtb[(size_t)tn * NH];

        float xdt = xin * dt;
        float ps;
        h[0] = fmaf(h[0], da, xdt * B0.x); ps = h[0] * C0.x;
        h[1] = fmaf(h[1], da, xdt * B0.y); ps = fmaf(h[1], C0.y, ps);
        h[2] = fmaf(h[2], da, xdt * B0.z); ps = fmaf(h[2], C0.z, ps);
        h[3] = fmaf(h[3], da, xdt * B0.w); ps = fmaf(h[3], C0.w, ps);
        h[4] = fmaf(h[4], da, xdt * B1.x); ps = fmaf(h[4], C1.x, ps);
        h[5] = fmaf(h[5], da, xdt * B1.y); ps = fmaf(h[5], C1.y, ps);
        h[6] = fmaf(h[6], da, xdt * B1.z); ps = fmaf(h[6], C1.z, ps);
        h[7] = fmaf(h[7], da, xdt * B1.w); ps = fmaf(h[7], C1.w, ps);

        ps += __shfl_xor(ps, 1);
        ps += __shfl_xor(ps, 2);
        ps += __shfl_xor(ps, 4);
        ps += __shfl_xor(ps, 8);
        if (jg == 0) yb[(size_t)t * DIP] = ps + Dh * xin;

        B0 = nB0; B1 = nB1; C0 = nC0; C1 = nC1;
        xin = nx; da = nda; dt = ndt;
    }
}

// ---------------- Kernel 6: gating + RMSNorm -> bf16 g ----------------
__global__ __launch_bounds__(256) void gate_rms_kernel(const float* __restrict__ zx,
                                                       const float* __restrict__ rw,
                                                       __hip_bfloat16* __restrict__ gq) {
    int m = blockIdx.x;
    int tid = threadIdx.x;
    const float* yr = zx + (size_t)m * DIP + DI;
    const float* zr = zx + (size_t)m * DIP;
    int base = tid * 8;
    float gv[8];
    float ss = 0.f;
    float4 ya = *(const float4*)(yr + base);
    float4 yb4 = *(const float4*)(yr + base + 4);
    float4 za = *(const float4*)(zr + base);
    float4 zb4 = *(const float4*)(zr + base + 4);
    float yv[8] = {ya.x, ya.y, ya.z, ya.w, yb4.x, yb4.y, yb4.z, yb4.w};
    float zv[8] = {za.x, za.y, za.z, za.w, zb4.x, zb4.y, zb4.z, zb4.w};
#pragma unroll
    for (int i = 0; i < 8; i++) {
        float sg = 1.f / (1.f + expf(-zv[i]));
        float gg = yv[i] * zv[i] * sg;
        gv[i] = gg;
        ss += gg * gg;
    }
#pragma unroll
    for (int off = 1; off < 64; off <<= 1) ss += __shfl_xor(ss, off);
    __shared__ float red[4];
    int w = tid >> 6;
    if ((tid & 63) == 0) red[w] = ss;
    __syncthreads();
    float tot = red[0] + red[1] + red[2] + red[3];
    float r = rsqrtf(tot * (1.f / DI) + 1e-5f);
#pragma unroll
    for (int i = 0; i < 8; i += 2) {
        __hip_bfloat162 p;
        p.x = __float2bfloat16(gv[i] * r * rw[base + i]);
        p.y = __float2bfloat16(gv[i + 1] * r * rw[base + i + 1]);
        *(__hip_bfloat162*)(gq + (size_t)m * DI + base + i) = p;
    }
}

// ---------------- Kernel 7: GEMM2 bf16 MFMA (transposed store) ----------------
// D[m][j] = sum_k gq[m][k] * Wob[j][k].  Store float4 along t into out[b,j,t].
__global__ __launch_bounds__(256) void gemm2_mfma(const __hip_bfloat16* __restrict__ gq,
                                                  const __hip_bfloat16* __restrict__ Wob,
                                                  float* __restrict__ out) {
    __shared__ short As[128][64];   // g rows (m)
    __shared__ short Bs[128][64];   // W rows (j)
    int tid = threadIdx.x;
    int lane = tid & 63;
    int wave = tid >> 6;
    int wr = wave >> 1, wc = wave & 1;
    int m0 = blockIdx.x * 128;
    int j0 = blockIdx.y * 128;
    int srow = tid >> 3;
    int skc = (tid & 7) * 8;

    f32x4 acc[4][4] = {};

    for (int k0 = 0; k0 < DI; k0 += 64) {
        __syncthreads();
#pragma unroll
        for (int q = 0; q < 4; q++) {
            gload16(gq + (size_t)(m0 + q * 32 + srow) * DI + k0 + skc,
                    ((short*)As) + q * 2048 + wave * 512);
            gload16(Wob + (size_t)(j0 + q * 32 + srow) * DI + k0 + skc,
                    ((short*)Bs) + q * 2048 + wave * 512);
        }
        asm volatile("s_waitcnt vmcnt(0)" ::: "memory");
        __syncthreads();
#pragma unroll
        for (int ks = 0; ks < 2; ks++) {
            bf16x8 af[4], bfr[4];
#pragma unroll
            for (int i = 0; i < 4; i++)
                af[i] = *(const bf16x8*)&As[wr * 64 + i * 16 + (lane & 15)][ks * 32 + (lane >> 4) * 8];
#pragma unroll
            for (int n = 0; n < 4; n++)
                bfr[n] = *(const bf16x8*)&Bs[wc * 64 + n * 16 + (lane & 15)][ks * 32 + (lane >> 4) * 8];
#pragma unroll
            for (int i = 0; i < 4; i++)
#pragma unroll
                for (int n = 0; n < 4; n++)
                    acc[i][n] = __builtin_amdgcn_mfma_f32_16x16x32_bf16(af[i], bfr[n], acc[i][n], 0, 0, 0);
        }
    }
#pragma unroll
    for (int i = 0; i < 4; i++) {
        int m = m0 + wr * 64 + i * 16 + ((lane >> 4) << 2);
        int b = m >> 12;
        int t = m & 4095;
#pragma unroll
        for (int n = 0; n < 4; n++) {
            int j = j0 + wc * 64 + n * 16 + (lane & 15);
            *(f32x4*)(out + (size_t)b * DM * TT + (size_t)j * TT + t) = acc[i][n];
        }
    }
}

extern "C" void kernel_launch(void* const* d_in, const int* in_sizes, int n_in,
                              void* d_out, int out_size, void* d_ws, size_t ws_size,
                              hipStream_t stream) {
    const float* x       = (const float*)d_in[0];
    const float* ln_w    = (const float*)d_in[1];
    const float* ln_b    = (const float*)d_in[2];
    const float* W_in    = (const float*)d_in[3];
    const float* conv_w  = (const float*)d_in[4];
    const float* conv_b  = (const float*)d_in[5];
    const float* dt_bias = (const float*)d_in[6];
    const float* A_log   = (const float*)d_in[7];
    const float* Dp      = (const float*)d_in[8];
    const float* rms_w   = (const float*)d_in[9];
    const float* W_out   = (const float*)d_in[10];
    const float* h0      = (const float*)d_in[11];

    float* out = (float*)d_out;
    float* hT = out + (size_t)BB * DM * TT;

    char* ws = (char*)d_ws;
    // Total footprint: 238,094,336 bytes (identical to proven round-4 layout).
    float* mu  = (float*)(ws + 0);            //      32,768
    float* rs  = (float*)(ws + 32768);        //      32,768
    float* zx  = (float*)(ws + 65536);        // 143,654,912  (B,T,4384) f32
    // xBC region [143,720,448 .. 219,217,920) — time-multiplexed:
    //   phase A (pre-conv):  Wb bf16 [4480][1024] = 9,175,040 B at +0
    //   phase B (conv..scan_emit): xBC f32 (B,T,2304) = 75,497,472 B
    //   phase C (post-scan): gq bf16 [8192][2048] = 33,554,432 B at +0
    //                        Wob bf16 [1024][2048] = 4,194,304 B at +41,943,040
    float* xBC = (float*)(ws + 143720448);
    __hip_bfloat16* Wb  = (__hip_bfloat16*)(ws + 143720448);
    __hip_bfloat16* gq  = (__hip_bfloat16*)(ws + 143720448);
    __hip_bfloat16* Wob = (__hip_bfloat16*)(ws + 143720448 + 41943040);
    float* dAb = (float*)(ws + 219217920);    //   1,048,576  (B,T,32)
    float* dtv = (float*)(ws + 220266496);    //   1,048,576  (B,T,32)
    // shared slab: xn bf16 [8192][1024] (pre-gemm1) / S f32 (scan) — disjoint lifetimes
    __hip_bfloat16* xnb = (__hip_bfloat16*)(ws + 221315072);   // 16,777,216
    float* S   = (float*)(ws + 221315072);
    float* P   = (float*)(ws + 238092288);    //       2,048

    ln_stats_kernel<<<dim3(TT / 64, BB), 64, 0, stream>>>(x, mu, rs);
    xn_kernel<<<dim3(TT / 64, DM / 64, BB), 256, 0, stream>>>(x, mu, rs, ln_w, ln_b, xnb);
    cvt_pad_kernel<<<(NP1 * DM) / 1024, 256, 0, stream>>>(W_in, Wb, DIP * DM, NP1 * DM);
    gemm1_mfma<<<dim3(NP1 / 128, (BB * TT) / 128), 256, 0, stream>>>(Wb, xnb, zx);
    gemm1_kernel<<<dim3(1, (BB * TT) / 64), 256, 0, stream>>>(x, mu, rs, ln_w, ln_b, W_in, zx, 4352);
    conv_kernel<<<(BB * TT * CD) / 256, 256, 0, stream>>>(zx, conv_w, conv_b, xBC);
    dt_kernel<<<(BB * TT * NH) / 256, 256, 0, stream>>>(zx, dt_bias, A_log, dtv, dAb);
    scan_reduce_kernel<<<dim3(16 * NC, NH, BB), 64, 0, stream>>>(xBC, dAb, dtv, S, P);
    scan_combine_kernel<<<(int)(SELEMS / 256), 256, 0, stream>>>(h0, P, S, hT);
    scan_emit_kernel<<<dim3(16 * NC, NH, BB), 64, 0, stream>>>(xBC, dAb, dtv, S, Dp, zx);
    cvt_pad_kernel<<<(DM * DI) / 1024, 256, 0, stream>>>(W_out, Wob, DM * DI, DM * DI);
    gate_rms_kernel<<<BB * TT, 256, 0, stream>>>(zx, rms_w, gq);
    gemm2_mfma<<<dim3((BB * TT) / 128, DM / 128), 256, 0, stream>>>(gq, Wob, out);
}